// Round 11
// baseline (2412.035 us; speedup 1.0000x reference)
//
#include <hip/hip_runtime.h>
#include <hip/hip_bf16.h>
#include <math.h>

#define SEQ   32
#define BATCH 1024
#define NN    19
#define HH    128
#define NB    2            /* batch elements per block */
#define MR    (NB*NN)      /* 38 rows per block */
#define SAS   264          /* sA row stride (bf16): 528 B = 16B-aligned, 4-bank shift */
#define H0S   128          /* h0 row stride (bf16) */
#define H1S   132          /* h1 row stride (f32) */
#define UBS   128          /* ub row stride (bf16) */
#define NBLK  (BATCH/NB)   /* 512 blocks, 2 per CU */
#define NT    512          /* 8 waves, with 2 blocks/CU -> 4 waves/SIMD */
#define UST_S 40           /* Ust col stride (elems): 80 B */

#define OFF_G0 0
#define OFF_C0 122880
#define OFF_G1 184320
#define OFF_C1 380928
#define WTOT   479232      /* total weight elems (bf16) */

/* LDS map (NB=2, fits 2 blocks/CU: 81272 <= 81920).
   ORDER MATTERS: MFMA A-frag reads touch sA rows 40-47 (mt2 tail), which
   overrun into ub — always-finite bf16 (zero-init, then sigmoid outputs);
   those products land in acc rows >= 38 and are discarded by the gm<MR
   guard.  Do not reorder sA/ub.
   h0  @     0  38*128*2 =  9728
   h1  @  9728  38*132*4 = 20064   (end 29792)
   sA  @ 29792  40*264*2 = 21120   (end 50912; rows 38-39 stay zero)
   ub  @ 50912  38*128*2 =  9728   (end 60640)
   sbf @ 60640  2*5*512*2= 10240   (end 70880; Tblk MFMA A-frags)
   Ust @ 70880  8*16*40*2= 10240   (end 81120; per-wave mixing scratch)
   xp  @ 81120  38*4     =   152   (end 81272)  */
#define OFF_H0  0
#define OFF_H1  9728
#define OFF_SA  29792
#define OFF_UB  50912
#define OFF_SBF 60640
#define OFF_UST 70880
#define OFF_XP  81120
#define LDS_BYTES 81272

// Weights + Chebyshev block-diag fragments in device-global (L2-resident).
__device__ unsigned short g_wall[WTOT];
/* g_sbf: MFMA A-fragments of Tblk1 = blockdiag(S,S) (frags 0..4) and
   Tblk2 = blockdiag(2S^2-I) (frags 5..9), fragment-major [frag][lane][8].
   Frag (mt,kt) order: (0,0),(1,0),(2,0),(1,1),(2,1). */
__device__ unsigned short g_sbf[2*5*512];

typedef __attribute__((ext_vector_type(8))) short  bf16x8;
typedef __attribute__((ext_vector_type(4))) short  bf16x4;
typedef __attribute__((ext_vector_type(4))) float  f32x4;

__device__ __forceinline__ unsigned short f2bf(float v) {
    __hip_bfloat16 b = __float2bfloat16(v);
    return *reinterpret_cast<unsigned short*>(&b);
}
__device__ __forceinline__ float bf2f(unsigned short u) {
    unsigned int x = ((unsigned int)u) << 16;
    return __uint_as_float(x);
}

// ---------------------------------------------------------------------------
// Setup 1: weight reorder/transpose into g_wall.
// Layer-0 (l0=1) K layout is [h(0..127) | x(128) | pad] so staging vectorizes.
// ---------------------------------------------------------------------------
__global__ __launch_bounds__(256) void wconv_kernel(
    const float* __restrict__ W, int F, int O, int KP, int off, int l0)
{
    int idx = blockIdx.x*256 + threadIdx.x;
    int total = 3*O*KP;
    if (idx >= total) return;
    int j   = idx / (O*KP);
    int r   = idx - j*(O*KP);
    int col = r / KP;
    int k   = r - col*KP;
    int src;
    if (l0) src = (k < HH) ? k+1 : ((k == HH) ? 0 : -1);
    else    src = (k < F) ? k : -1;
    float v = (src >= 0) ? W[(size_t)(j*F + src)*O + col] : 0.f;
    g_wall[off + idx] = f2bf(v);
}

// ---------------------------------------------------------------------------
// Setup 2: Tblk fragments (48x64 block-diag over 2 batches, zero-padded).
// A-frag layout (mfma_16x16x32): lane l, elem e ->
//   Tblk[fmt*16 + (l&15)][fkt*32 + (l>>4)*8 + e]
// ---------------------------------------------------------------------------
__global__ __launch_bounds__(256) void sbf_kernel(const float* __restrict__ S)
{
    __shared__ float sS[NN*NN], sS2[NN*NN];
    int tid = threadIdx.x;
    for (int i = tid; i < NN*NN; i += 256) sS[i] = S[i];
    __syncthreads();
    for (int i = tid; i < NN*NN; i += 256) {
        int m = i/NN, n = i - m*NN;
        float a = 0.f;
        for (int k = 0; k < NN; ++k) a += sS[m*NN+k]*sS[k*NN+n];
        sS2[i] = a;
    }
    __syncthreads();
    const int fmt[5] = {0,1,2, 1,2};
    const int fkt[5] = {0,0,0, 1,1};
    for (int idx = tid; idx < 2*5*512; idx += 256) {
        int mat = idx / 2560;
        int rem = idx - mat*2560;
        int i   = rem >> 9;
        int l   = (rem >> 3) & 63;
        int e   = rem & 7;
        int r   = fmt[i]*16 + (l & 15);
        int k   = fkt[i]*32 + (l >> 4)*8 + e;
        float v = 0.f;
        if (r < MR && k < MR) {
            int b = r / NN, m = r - b*NN;
            int k0 = b*NN;
            if (k >= k0 && k < k0 + NN) {
                int n = k - k0;
                v = (mat == 0) ? sS[m*NN+n]
                               : (2.f*sS2[m*NN+n] - ((m==n)?1.f:0.f));
            }
        }
        g_sbf[idx] = f2bf(v);
    }
}

// ---------------------------------------------------------------------------
// Compute one 16-col slice (cols [sgo, sgo+16)) of a gconv:
//   acc[j][mt] = X @ Wj  (fused 3-segment K-loop, depth-2 weight ring)
//   then acc[0] += Tblk1@acc[1] + Tblk2@acc[2] via per-wave Ust scratch.
// Result in acc[0][mt].  3 mt tiles cover 48 rows (rows >= 38 are junk,
// discarded by the caller's gm<MR guard).
// ---------------------------------------------------------------------------
template<int KS, int OC>
__device__ __forceinline__ void gcompute(
    f32x4 (&acc)[3][3],
    const unsigned short* __restrict__ BT,
    const unsigned short* __restrict__ sA,
    const unsigned short* __restrict__ sbf,
    unsigned short* __restrict__ Ust,
    int sgo, int lane)
{
    constexpr int KP = KS*32;
    const int r16 = lane & 15, quad = lane >> 4;

    const unsigned short* wb[3];
    #pragma unroll
    for (int j = 0; j < 3; ++j)
        wb[j] = BT + (size_t)(j*OC + sgo + r16)*KP + quad*8;

    #pragma unroll
    for (int j = 0; j < 3; ++j)
        #pragma unroll
        for (int mt = 0; mt < 3; ++mt) acc[j][mt] = (f32x4)0.f;

    bf16x8 ring[2][3];
    #pragma unroll
    for (int j = 0; j < 3; ++j) {
        ring[0][j] = *(const bf16x8*)(wb[j]);
        if (KS > 1) ring[1][j] = *(const bf16x8*)(wb[j] + 32);
    }
    #pragma unroll
    for (int ks = 0; ks < KS; ++ks) {
        bf16x8 bcur[3];
        #pragma unroll
        for (int j = 0; j < 3; ++j) bcur[j] = ring[ks & 1][j];
        if (ks + 2 < KS) {
            #pragma unroll
            for (int j = 0; j < 3; ++j)
                ring[ks & 1][j] = *(const bf16x8*)(wb[j] + (ks + 2)*32);
        }
        #pragma unroll
        for (int mt = 0; mt < 3; ++mt) {
            bf16x8 af = *(const bf16x8*)&sA[(mt*16 + r16)*SAS + ks*32 + quad*8];
            #pragma unroll
            for (int j = 0; j < 3; ++j)
                acc[j][mt] = __builtin_amdgcn_mfma_f32_16x16x32_bf16(
                    af, bcur[j], acc[j][mt], 0, 0, 0);
        }
    }

    /* mixing: acc[0] += Tblk_jj @ acc[jj].  Per kt tile (32 U-rows): stage
       acc col-major into Ust (b64), read back as B-frag (b128).  kt1 has
       only mt2; stale tile rows 16-31 multiply zero Tblk cols. */
    constexpr int ktCnt[2]   = {3,2};
    constexpr int ktMT[2][3] = {{0,1,2},{1,2,0}};
    constexpr int ktF0[2]    = {0,3};
    #pragma unroll
    for (int jj = 1; jj <= 2; ++jj) {
        #pragma unroll
        for (int kt = 0; kt < 2; ++kt) {
            #pragma unroll
            for (int mtk = 0; mtk < 2; ++mtk) {
                if (kt*2 + mtk < 3) {
                    bf16x4 pv;
                    pv[0] = (short)f2bf(acc[jj][kt*2+mtk][0]);
                    pv[1] = (short)f2bf(acc[jj][kt*2+mtk][1]);
                    pv[2] = (short)f2bf(acc[jj][kt*2+mtk][2]);
                    pv[3] = (short)f2bf(acc[jj][kt*2+mtk][3]);
                    *(bf16x4*)&Ust[r16*UST_S + mtk*16 + quad*4] = pv;
                }
            }
            bf16x8 Bf = *(const bf16x8*)&Ust[r16*UST_S + quad*8];
            #pragma unroll
            for (int q = 0; q < ktCnt[kt]; ++q) {
                const int mt = ktMT[kt][q];
                bf16x8 af = *(const bf16x8*)
                    &sbf[((jj-1)*5 + ktF0[kt] + q)*512 + lane*8];
                acc[0][mt] = __builtin_amdgcn_mfma_f32_16x16x32_bf16(
                    af, Bf, acc[0][mt], 0, 0, 0);
            }
        }
    }
}

// ---------------------------------------------------------------------------
// Persistent kernel: 512 blocks x 512 threads; 2 blocks/CU (two independent
// barrier domains per CU -> stall overlap), 4 waves/SIMD.
// ---------------------------------------------------------------------------
__global__ __launch_bounds__(NT)
__attribute__((amdgpu_waves_per_eu(4, 4)))
void dcgru_persistent(
    const float* __restrict__ ihs,
    const float* __restrict__ bg0, const float* __restrict__ bc0,
    const float* __restrict__ bg1, const float* __restrict__ bc1,
    const float* __restrict__ Wp, const float* __restrict__ bp,
    float* __restrict__ out)
{
    extern __shared__ char smem[];
    unsigned short* h0  = (unsigned short*)(smem + OFF_H0);
    float*          h1  = (float*)(smem + OFF_H1);
    unsigned short* sA  = (unsigned short*)(smem + OFF_SA);
    unsigned short* ub  = (unsigned short*)(smem + OFF_UB);
    unsigned short* sbf = (unsigned short*)(smem + OFF_SBF);
    float*       xprev  = (float*)(smem + OFF_XP);

    const int tid  = threadIdx.x;
    const int lane = tid & 63;
    const int w    = tid >> 6;          /* 0..7 */
    const int r16  = lane & 15, quad = lane >> 4;
    const int bb   = blockIdx.x * NB;
    unsigned short* Ust = (unsigned short*)(smem + OFF_UST) + w*(16*UST_S);

    const unsigned short* BTg0 = g_wall + OFF_G0;
    const unsigned short* BTc0 = g_wall + OFF_C0;
    const unsigned short* BTg1 = g_wall + OFF_G1;
    const unsigned short* BTc1 = g_wall + OFF_C1;

    for (int i = tid; i < MR*HH; i += NT) {
        h0[(i >> 7)*H0S + (i & 127)] = f2bf(ihs[(size_t)bb*2432 + i]);
        h1[(i >> 7)*H1S + (i & 127)] = ihs[(size_t)(BATCH + bb)*2432 + i];
    }
    for (int i = tid; i < MR; i += NT) xprev[i] = 0.f;
    /* zero sA (rows 38-39 pad + cols stay zero), ub (read via sA row
       overrun before first gate), Ust (stale reads must be finite) */
    for (int i = tid; i < 40*SAS/8; i += NT) ((bf16x8*)sA)[i] = (bf16x8)(short)0;
    for (int i = tid; i < MR*UBS/8; i += NT) ((bf16x8*)ub)[i] = (bf16x8)(short)0;
    for (int i = tid; i < 8*16*UST_S/8; i += NT)
        ((bf16x8*)(smem + OFF_UST))[i] = (bf16x8)(short)0;
    for (int i = tid; i < 2*5*512/8; i += NT)
        ((bf16x8*)sbf)[i] = ((const bf16x8*)g_sbf)[i];
    const float wp0 = Wp[lane], wp1 = Wp[64 + lane], bpv = bp[0];
    __syncthreads();

    for (int t = 0; t < SEQ; ++t) {
        // ---- stage layer 0: sA = [h0 | x | 0-pad]  (K = 160) ----
        for (int i = tid; i < MR*16; i += NT) {
            int row = i >> 4, ch = i & 15;
            *(bf16x8*)&sA[row*SAS + ch*8] =
                *(const bf16x8*)&h0[row*H0S + ch*8];
        }
        for (int i = tid; i < MR*4; i += NT) {
            int row = i >> 2, ch = i & 3;
            bf16x8 v = (bf16x8)(short)0;
            if (ch == 0) v[0] = (short)f2bf(xprev[row]);
            *(bf16x8*)&sA[row*SAS + HH + ch*8] = v;
        }
        __syncthreads();

        // ---- gate0: u-pass (cols 128-255) then r-pass (cols 0-127) ----
        {
            f32x4 a[3][3];
            gcompute<5,256>(a, BTg0, sA, sbf, Ust, 128 + w*16, lane);
            float bv = bg0[128 + w*16 + r16];
            #pragma unroll
            for (int mt = 0; mt < 3; ++mt)
                #pragma unroll
                for (int reg = 0; reg < 4; ++reg) {
                    int gm = mt*16 + quad*4 + reg;
                    if (gm < MR) {
                        float v = a[0][mt][reg] + bv;
                        ub[gm*UBS + w*16 + r16] = f2bf(1.f/(1.f + __expf(-v)));
                    }
                }
        }
        {
            f32x4 a[3][3];
            gcompute<5,256>(a, BTg0, sA, sbf, Ust, w*16, lane);
            float bv = bg0[w*16 + r16];
            __syncthreads();   /* all waves' sA reads complete */
            #pragma unroll
            for (int mt = 0; mt < 3; ++mt)
                #pragma unroll
                for (int reg = 0; reg < 4; ++reg) {
                    int gm = mt*16 + quad*4 + reg;
                    if (gm < MR) {
                        int o = w*16 + r16;
                        float v = a[0][mt][reg] + bv;
                        float sg = 1.f/(1.f + __expf(-v));
                        sA[gm*SAS + o] = f2bf(sg * bf2f(h0[gm*H0S + o]));
                    }
                }
        }
        __syncthreads();

        // ---- cand0 (cols 0-127): h0 update ----
        {
            f32x4 a[3][3];
            gcompute<5,128>(a, BTc0, sA, sbf, Ust, w*16, lane);
            float bv = bc0[w*16 + r16];
            #pragma unroll
            for (int mt = 0; mt < 3; ++mt)
                #pragma unroll
                for (int reg = 0; reg < 4; ++reg) {
                    int gm = mt*16 + quad*4 + reg;
                    if (gm < MR) {
                        int o = w*16 + r16;
                        float v = a[0][mt][reg] + bv;
                        float c = 2.f/(1.f + __expf(-2.f*v)) - 1.f;
                        float u = bf2f(ub[gm*UBS + o]);
                        float ho = bf2f(h0[gm*H0S + o]);
                        h0[gm*H0S + o] = f2bf(u*ho + (1.f - u)*c);
                    }
                }
        }
        __syncthreads();

        // ---- stage layer 1: sA = [h0 | h1]  (K = 256) ----
        for (int i = tid; i < MR*16; i += NT) {
            int row = i >> 4, ch = i & 15;
            *(bf16x8*)&sA[row*SAS + ch*8] =
                *(const bf16x8*)&h0[row*H0S + ch*8];
        }
        for (int i = tid; i < MR*16; i += NT) {
            int row = i >> 4, ch = i & 15;
            const float* hp = &h1[row*H1S + ch*8];
            f32x4 x0 = *(const f32x4*)hp;
            f32x4 x1 = *(const f32x4*)(hp + 4);
            bf16x8 v;
            v[0] = (short)f2bf(x0[0]); v[1] = (short)f2bf(x0[1]);
            v[2] = (short)f2bf(x0[2]); v[3] = (short)f2bf(x0[3]);
            v[4] = (short)f2bf(x1[0]); v[5] = (short)f2bf(x1[1]);
            v[6] = (short)f2bf(x1[2]); v[7] = (short)f2bf(x1[3]);
            *(bf16x8*)&sA[row*SAS + HH + ch*8] = v;
        }
        __syncthreads();

        // ---- gate1: u-pass then r-pass (epilogue rewrites sA cols 128+) ----
        {
            f32x4 a[3][3];
            gcompute<8,256>(a, BTg1, sA, sbf, Ust, 128 + w*16, lane);
            float bv = bg1[128 + w*16 + r16];
            #pragma unroll
            for (int mt = 0; mt < 3; ++mt)
                #pragma unroll
                for (int reg = 0; reg < 4; ++reg) {
                    int gm = mt*16 + quad*4 + reg;
                    if (gm < MR) {
                        float v = a[0][mt][reg] + bv;
                        ub[gm*UBS + w*16 + r16] = f2bf(1.f/(1.f + __expf(-v)));
                    }
                }
        }
        {
            f32x4 a[3][3];
            gcompute<8,256>(a, BTg1, sA, sbf, Ust, w*16, lane);
            float bv = bg1[w*16 + r16];
            __syncthreads();   /* all waves' sA reads complete */
            #pragma unroll
            for (int mt = 0; mt < 3; ++mt)
                #pragma unroll
                for (int reg = 0; reg < 4; ++reg) {
                    int gm = mt*16 + quad*4 + reg;
                    if (gm < MR) {
                        int o = w*16 + r16;
                        float v = a[0][mt][reg] + bv;
                        float sg = 1.f/(1.f + __expf(-v));
                        sA[gm*SAS + HH + o] = f2bf(sg * h1[gm*H1S + o]);
                    }
                }
        }
        __syncthreads();

        // ---- cand1 (cols 0-127): h1 update ----
        {
            f32x4 a[3][3];
            gcompute<8,128>(a, BTc1, sA, sbf, Ust, w*16, lane);
            float bv = bc1[w*16 + r16];
            #pragma unroll
            for (int mt = 0; mt < 3; ++mt)
                #pragma unroll
                for (int reg = 0; reg < 4; ++reg) {
                    int gm = mt*16 + quad*4 + reg;
                    if (gm < MR) {
                        int o = w*16 + r16;
                        float v = a[0][mt][reg] + bv;
                        float c = 2.f/(1.f + __expf(-2.f*v)) - 1.f;
                        float u = bf2f(ub[gm*UBS + o]);
                        float ho = h1[gm*H1S + o];
                        h1[gm*H1S + o] = u*ho + (1.f - u)*c;
                    }
                }
        }
        __syncthreads();

        // ---- projection: wave w -> rows [w*5, w*5+5) ----
        {
            int rA = w*5;
            for (int rr = rA; rr < rA + 5 && rr < MR; ++rr) {
                int b = rr / NN, n = rr - b*NN;
                float s = h1[rr*H1S + lane]*wp0 + h1[rr*H1S + 64 + lane]*wp1;
                #pragma unroll
                for (int off = 32; off; off >>= 1) s += __shfl_down(s, off, 64);
                if (lane == 0) {
                    float v = s + bpv;
                    out[((size_t)t*BATCH + bb + b)*NN + n] = v;
                    xprev[rr] = v;
                }
            }
        }
        __syncthreads();
    }
}

// ---------------------------------------------------------------------------
extern "C" void kernel_launch(void* const* d_in, const int* in_sizes, int n_in,
                              void* d_out, int out_size, void* d_ws, size_t ws_size,
                              hipStream_t stream) {
    const float* ihs = (const float*)d_in[1];
    const float* S   = (const float*)d_in[2];
    const float* Wg0 = (const float*)d_in[3];
    const float* bg0 = (const float*)d_in[4];
    const float* Wc0 = (const float*)d_in[5];
    const float* bc0 = (const float*)d_in[6];
    const float* Wg1 = (const float*)d_in[7];
    const float* bg1 = (const float*)d_in[8];
    const float* Wc1 = (const float*)d_in[9];
    const float* bc1 = (const float*)d_in[10];
    const float* Wp  = (const float*)d_in[11];
    const float* bp  = (const float*)d_in[12];
    float* out = (float*)d_out;

    sbf_kernel<<<1, 256, 0, stream>>>(S);
    wconv_kernel<<<(3*256*160+255)/256, 256, 0, stream>>>(Wg0, 129, 256, 160, OFF_G0, 1);
    wconv_kernel<<<(3*128*160+255)/256, 256, 0, stream>>>(Wc0, 129, 128, 160, OFF_C0, 1);
    wconv_kernel<<<(3*256*256+255)/256, 256, 0, stream>>>(Wg1, 256, 256, 256, OFF_G1, 0);
    wconv_kernel<<<(3*128*256+255)/256, 256, 0, stream>>>(Wc1, 256, 128, 256, OFF_C1, 0);

    hipFuncSetAttribute((const void*)dcgru_persistent,
                        hipFuncAttributeMaxDynamicSharedMemorySize, LDS_BYTES);

    dcgru_persistent<<<NBLK, NT, LDS_BYTES, stream>>>(
        ihs, bg0, bc0, bg1, bc1, Wp, bp, out);
}